// Round 5
// baseline (671.255 us; speedup 1.0000x reference)
//
#include <hip/hip_runtime.h>

// SNN forward. conv2 + fc1 on MFMA bf16, 3-way weight splits (hi+lo+lolo).
// R5: conv2_fused restructured per-t (no spills, contiguous pool2 writes),
//     A-frag prefetch in both conv2 MFMA kernels.
//   conv1 stats -> bn1 -> fused conv1+BN+LIF+pool (bf16 spikes)
//   conv2 stats (MFMA) -> bn2 -> fused conv2+BN+LIF+pool (MFMA, v in regs)
//   fc1 MFMA (split-K=16, private partials) -> reduce+LIF -> fc2

#define LIF_STEP(vv, xx, ss) do { \
    vv = fmaf((xx) - vv, 0.5f, vv); \
    ss = (vv >= 1.0f) ? 1.0f : 0.0f; \
    vv = (vv >= 1.0f) ? 0.0f : vv; \
  } while (0)

typedef __attribute__((ext_vector_type(8))) short short8;
typedef __attribute__((ext_vector_type(4))) float f32x4;

__device__ __forceinline__ float bf2f(unsigned short u) {
  return __uint_as_float(((unsigned)u) << 16);
}
__device__ __forceinline__ unsigned short f2bf(float f) {
  return (unsigned short)(__float_as_uint(f) >> 16);  // exact for k/4 spike values
}

// ---- workspace layout (float-slot offsets) ----
// pool1 bf16 [1024 tb][8 cg][16 py][16 px][8 ci_l] = 16,777,216 u16
//   (region reused AFTER conv2 as fc1 partials f32 [16 kb][256 o][1024 tb])
// pool2 bf16 [1024 tb][64 s][128 ci]               =  8,388,608 u16
#define OFF_POOL1   0u
#define OFF_POOL2   8388608u
#define OFF_STATS   12582912u   // f32 768
#define OFF_FC1S    12583680u   // f32 262,144
#define OFF_A2      12845824u   // bf16 3x[18 kc][128 co][4 q][8 j]
#define OFF_B1      12956416u   // bf16 3x[256 kc][256 o][4 q][8 j]
// total 16,102,144 floats = 64.4 MB

__global__ __launch_bounds__(256) void zero_kernel(float* __restrict__ p, unsigned n) {
  unsigned i = blockIdx.x * 256u + threadIdx.x;
  if (i < n) p[i] = 0.0f;
}

// conv2_w [co 128][ci 64][dy 3][dx 3] fp32 -> 3-way bf16 split in MFMA A-frag order
__global__ __launch_bounds__(256) void prep_w2(const float* __restrict__ w, unsigned short* __restrict__ A2) {
  int i = blockIdx.x * 256 + threadIdx.x;
  if (i >= 73728) return;
  int co = i / 576, r = i - co * 576;
  int ci = r / 9, t9 = r - ci * 9;
  int k = t9 * 64 + ci;
  int kc = k >> 5, q = (k >> 3) & 3, j = k & 7;
  int off = ((kc * 128 + co) * 4 + q) * 8 + j;
  float wv = w[i];
  unsigned short hi = f2bf(wv);
  float rem = wv - bf2f(hi);
  unsigned short lo = f2bf(rem);
  float rem2 = rem - bf2f(lo);
  A2[off] = hi;
  A2[73728 + off] = lo;
  A2[147456 + off] = f2bf(rem2);
}

// fc1_w [o 256][k_orig 8192] -> 3-way split, permuted k_new = s*128+ci to match
// pool2's [s][ci] layout (k_orig = ci*64 + s).
__global__ __launch_bounds__(256) void prep_b1(const float* __restrict__ w, unsigned short* __restrict__ B1) {
  int i = blockIdx.x * 256 + threadIdx.x;   // 2,097,152 total
  int o = i >> 13, k_orig = i & 8191;
  int ci = k_orig >> 6, s = k_orig & 63;
  int k = s * 128 + ci;
  int kc = k >> 5, q = (k >> 3) & 3, j = k & 7;
  int off = ((kc * 256 + o) * 4 + q) * 8 + j;
  float wv = w[i];
  unsigned short hi = f2bf(wv);
  float rem = wv - bf2f(hi);
  unsigned short lo = f2bf(rem);
  float rem2 = rem - bf2f(lo);
  B1[off] = hi;
  B1[2097152 + off] = lo;
  B1[4194304 + off] = f2bf(rem2);
}

// ---- conv1 pass 1: stats only. (validated) ----
__global__ __launch_bounds__(256) void conv1_pass1(const float* __restrict__ x,
                                                   const float* __restrict__ w,
                                                   float* __restrict__ s_sum,
                                                   float* __restrict__ s_sq) {
  int tb = blockIdx.x;
  __shared__ float simg[3 * 32 * 36];
  int tid = threadIdx.x;
  const float* xb = x + tb * 3072;
  for (int i = tid; i < 3456; i += 256) {
    int ci = i / 1152, rem = i - ci * 1152;
    int y = rem / 36, px = rem - y * 36;
    int gx = px - 1;
    simg[i] = ((unsigned)gx < 32u) ? xb[(ci * 32 + y) * 32 + gx] : 0.0f;
  }
  __syncthreads();

  int cgrp = tid >> 3, rowthr = tid & 7;
  int c0 = cgrp * 2;
  float w0[27], w1[27];
#pragma unroll
  for (int j = 0; j < 27; ++j) { w0[j] = w[c0 * 27 + j]; w1[j] = w[c0 * 27 + 27 + j]; }

  float s1a = 0.f, s2a = 0.f, s1b = 0.f, s2b = 0.f;
  for (int task = 0; task < 8; ++task) {
    int y = rowthr + (task & 3) * 8;
    int x0 = (task >> 2) * 16;
    float acc0[16] = {0.f,0.f,0.f,0.f,0.f,0.f,0.f,0.f,0.f,0.f,0.f,0.f,0.f,0.f,0.f,0.f};
    float acc1[16] = {0.f,0.f,0.f,0.f,0.f,0.f,0.f,0.f,0.f,0.f,0.f,0.f,0.f,0.f,0.f,0.f};
#pragma unroll
    for (int ci = 0; ci < 3; ++ci) {
#pragma unroll
      for (int dy = 0; dy < 3; ++dy) {
        int yy = y + dy - 1;
        if (yy >= 0 && yy < 32) {
          const float* row = simg + (ci * 32 + yy) * 36 + x0;
          float rr[20];
#pragma unroll
          for (int q = 0; q < 5; ++q) {
            float4 f = *(const float4*)(row + q * 4);
            rr[q*4+0] = f.x; rr[q*4+1] = f.y; rr[q*4+2] = f.z; rr[q*4+3] = f.w;
          }
#pragma unroll
          for (int dx = 0; dx < 3; ++dx) {
            float wa = w0[ci*9 + dy*3 + dx], wb = w1[ci*9 + dy*3 + dx];
#pragma unroll
            for (int xi = 0; xi < 16; ++xi) {
              float v = rr[xi + dx];
              acc0[xi] = fmaf(wa, v, acc0[xi]);
              acc1[xi] = fmaf(wb, v, acc1[xi]);
            }
          }
        }
      }
    }
#pragma unroll
    for (int xi = 0; xi < 16; ++xi) {
      s1a += acc0[xi]; s2a = fmaf(acc0[xi], acc0[xi], s2a);
      s1b += acc1[xi]; s2b = fmaf(acc1[xi], acc1[xi], s2b);
    }
  }
#pragma unroll
  for (int off = 1; off < 8; off <<= 1) {
    s1a += __shfl_xor(s1a, off); s2a += __shfl_xor(s2a, off);
    s1b += __shfl_xor(s1b, off); s2b += __shfl_xor(s2b, off);
  }
  if (rowthr == 0) {
    atomicAdd(&s_sum[c0], s1a);     atomicAdd(&s_sq[c0], s2a);
    atomicAdd(&s_sum[c0 + 1], s1b); atomicAdd(&s_sq[c0 + 1], s2b);
  }
}

__global__ void finalize_bn(const float* __restrict__ sum, const float* __restrict__ sq,
                            const float* __restrict__ g, const float* __restrict__ b,
                            float* __restrict__ scale, float* __restrict__ shift, float inv_n) {
  int c = threadIdx.x;
  float mean = sum[c] * inv_n;
  float var = fmaxf(sq[c] * inv_n - mean * mean, 0.0f);
  float rstd = rsqrtf(var + 1e-5f);
  float sc = g[c] * rstd;
  scale[c] = sc;
  shift[c] = fmaf(-mean, sc, b[c]);
}

// ---- conv1 pass 2: fused conv+BN+LIF+pool -> pool1 [tb][cg][py][px][ci_l 8]. (validated) ----
__global__ __launch_bounds__(256) void conv1_fused(const float* __restrict__ x,
    const float* __restrict__ w, const float* __restrict__ scale, const float* __restrict__ shift,
    unsigned short* __restrict__ pool1) {
  int b = blockIdx.x >> 3, cg = blockIdx.x & 7;
  int tid = threadIdx.x;
  int co_l = tid >> 5;
  int co = cg * 8 + co_l;
  int y = tid & 31;
  __shared__ float simg[3 * 34 * 36];
  __shared__ unsigned short shp[2112];
  float wreg[27];
#pragma unroll
  for (int j = 0; j < 27; ++j) wreg[j] = w[co * 27 + j];
  float sc = scale[co], sh = shift[co];
  float v[32];
#pragma unroll
  for (int i = 0; i < 32; ++i) v[i] = 0.f;

  for (int t = 0; t < 8; ++t) {
    int tb = t * 128 + b;
    const float* xb = x + tb * 3072;
    __syncthreads();
    for (int i = tid; i < 3672; i += 256) {
      int ci = i / 1224, r = i - ci * 1224;
      int yy = r / 36, xx = r - yy * 36;
      int gy = yy - 1, gx = xx - 1;
      simg[i] = ((unsigned)gy < 32u && (unsigned)gx < 32u) ? xb[(ci * 32 + gy) * 32 + gx] : 0.f;
    }
    __syncthreads();
    float acc[32];
#pragma unroll
    for (int i = 0; i < 32; ++i) acc[i] = 0.f;
#pragma unroll
    for (int ci = 0; ci < 3; ++ci) {
#pragma unroll
      for (int dy = 0; dy < 3; ++dy) {
        const float* row = simg + (ci * 34 + y + dy) * 36;
        float rr[36];
#pragma unroll
        for (int q = 0; q < 9; ++q) {
          float4 f = *(const float4*)(row + q * 4);
          rr[q*4+0]=f.x; rr[q*4+1]=f.y; rr[q*4+2]=f.z; rr[q*4+3]=f.w;
        }
#pragma unroll
        for (int dx = 0; dx < 3; ++dx) {
          float wv = wreg[ci * 9 + dy * 3 + dx];
#pragma unroll
          for (int xx2 = 0; xx2 < 32; ++xx2)
            acc[xx2] = fmaf(wv, rr[xx2 + dx], acc[xx2]);
        }
      }
    }
    float hp[16];
#pragma unroll
    for (int px = 0; px < 16; ++px) {
      float s0, s1, xv;
      xv = fmaf(acc[2*px],   sc, sh); LIF_STEP(v[2*px],   xv, s0);
      xv = fmaf(acc[2*px+1], sc, sh); LIF_STEP(v[2*px+1], xv, s1);
      hp[px] = s0 + s1;
    }
    unsigned short ob[16];
#pragma unroll
    for (int px = 0; px < 16; ++px) {
      float sum = hp[px] + __shfl_xor(hp[px], 1);
      ob[px] = f2bf(0.25f * sum);
    }
    if ((y & 1) == 0) {
      int py = y >> 1;
#pragma unroll
      for (int px = 0; px < 16; ++px)
        shp[py * 132 + px * 8 + co_l] = ob[px];
    }
    __syncthreads();
    {
      int o = (tid >> 4) * 132 + (tid & 15) * 8;
      uint2 lo = *(const uint2*)&shp[o];
      uint2 hi = *(const uint2*)&shp[o + 4];
      *(uint4*)(pool1 + (size_t)tb * 16384 + cg * 2048 + tid * 8) = make_uint4(lo.x, lo.y, hi.x, hi.y);
    }
  }
}

// ---- conv2 pass 1 (MFMA): stats only. Block per tb image; A-frag prefetch. ----
__global__ __launch_bounds__(256, 2) void conv2_pass1_mfma(const unsigned short* __restrict__ pool1,
    const unsigned short* __restrict__ A2,
    float* __restrict__ s_sum, float* __restrict__ s_sq) {
  int tb = blockIdx.x;
  __shared__ unsigned short simg[18 * 8 * 18 * 8];   // 41,472 B
  int tid = threadIdx.x;
  const unsigned* src = (const unsigned*)(pool1 + (size_t)tb * 16384);
  unsigned* dstw = (unsigned*)simg;
  for (int i = tid; i < 10368; i += 256) {
    int j = i / 72, r = i - j * 72;
    int row = j >> 3, cg = j & 7;
    int xx = r >> 2, cp = r & 3;
    int yi = row - 1, gx = xx - 1;
    unsigned val = 0u;
    if ((unsigned)yi < 16u && (unsigned)gx < 16u)
      val = src[cg * 1024 + yi * 64 + gx * 4 + cp];
    dstw[i] = val;
  }
  __syncthreads();

  int wave = tid >> 6, lane = tid & 63;
  int xl = lane & 15, q = lane >> 4;
  int m0 = wave * 32;
  f32x4 acc[2][16];
#pragma unroll
  for (int mt = 0; mt < 2; ++mt)
#pragma unroll
    for (int yy = 0; yy < 16; ++yy) acc[mt][yy] = (f32x4){0.f, 0.f, 0.f, 0.f};

  short8 a_cur[2][3];
#pragma unroll
  for (int mt = 0; mt < 2; ++mt) {
    int aoff = ((0 * 128 + m0 + mt * 16 + xl) * 4 + q) * 8;
    a_cur[mt][0] = *(const short8*)(A2 + aoff);
    a_cur[mt][1] = *(const short8*)(A2 + 73728 + aoff);
    a_cur[mt][2] = *(const short8*)(A2 + 147456 + aoff);
  }

#pragma unroll 1
  for (int kc = 0; kc < 18; ++kc) {
    short8 a_nxt[2][3];
    if (kc < 17) {
#pragma unroll
      for (int mt = 0; mt < 2; ++mt) {
        int aoff = (((kc + 1) * 128 + m0 + mt * 16 + xl) * 4 + q) * 8;
        a_nxt[mt][0] = *(const short8*)(A2 + aoff);
        a_nxt[mt][1] = *(const short8*)(A2 + 73728 + aoff);
        a_nxt[mt][2] = *(const short8*)(A2 + 147456 + aoff);
      }
    } else {
#pragma unroll
      for (int mt = 0; mt < 2; ++mt)
#pragma unroll
        for (int sv = 0; sv < 3; ++sv) a_nxt[mt][sv] = a_cur[mt][sv];
    }
    int tap = kc >> 1;
    int dy = tap / 3, dx = tap - dy * 3;
    int cgq = (kc & 1) * 4 + q;
#pragma unroll
    for (int yy = 0; yy < 16; ++yy) {
      int baddr = (((yy + dy) * 8 + cgq) * 18 + (xl + dx)) * 8;
      short8 bb = *(const short8*)(simg + baddr);
#pragma unroll
      for (int mt = 0; mt < 2; ++mt) {
        acc[mt][yy] = __builtin_amdgcn_mfma_f32_16x16x32_bf16(a_cur[mt][0], bb, acc[mt][yy], 0, 0, 0);
        acc[mt][yy] = __builtin_amdgcn_mfma_f32_16x16x32_bf16(a_cur[mt][1], bb, acc[mt][yy], 0, 0, 0);
        acc[mt][yy] = __builtin_amdgcn_mfma_f32_16x16x32_bf16(a_cur[mt][2], bb, acc[mt][yy], 0, 0, 0);
      }
    }
#pragma unroll
    for (int mt = 0; mt < 2; ++mt)
#pragma unroll
      for (int sv = 0; sv < 3; ++sv) a_cur[mt][sv] = a_nxt[mt][sv];
  }
#pragma unroll
  for (int mt = 0; mt < 2; ++mt)
#pragma unroll
    for (int reg = 0; reg < 4; ++reg) {
      float s1 = 0.f, s2 = 0.f;
#pragma unroll
      for (int yy = 0; yy < 16; ++yy) {
        float val = acc[mt][yy][reg];
        s1 += val; s2 = fmaf(val, val, s2);
      }
#pragma unroll
      for (int off = 1; off < 16; off <<= 1) {
        s1 += __shfl_xor(s1, off); s2 += __shfl_xor(s2, off);
      }
      if (xl == 0) {
        int co = m0 + mt * 16 + q * 4 + reg;
        atomicAdd(&s_sum[co], s1);
        atomicAdd(&s_sq[co], s2);
      }
    }
}

// ---- conv2 pass 2 (MFMA): fused conv+BN+LIF+pool, one t per stage (low reg pressure). ----
// Block = (b, q4). pool2 layout [tb][s 64][ci 128] -> 4 KB contiguous writes per (block,t).
__global__ __launch_bounds__(256, 2) void conv2_fused_mfma(const unsigned short* __restrict__ pool1,
    const unsigned short* __restrict__ A2,
    const float* __restrict__ scale, const float* __restrict__ shift,
    unsigned short* __restrict__ pool2) {
  int b = blockIdx.x >> 2, q4 = blockIdx.x & 3;
  __shared__ unsigned short simg[6 * 8 * 18 * 8];   // 13,824 B
  __shared__ unsigned short shout[16 * 136];        // [s_l 16][co 128], row stride 136
  int tid = threadIdx.x, wave = tid >> 6, lane = tid & 63;
  int xl = lane & 15, q = lane >> 4;
  int m0 = wave * 32;

  float scr[2][4], shr[2][4];
#pragma unroll
  for (int mt = 0; mt < 2; ++mt)
#pragma unroll
    for (int reg = 0; reg < 4; ++reg) {
      int co = m0 + mt * 16 + q * 4 + reg;
      scr[mt][reg] = scale[co]; shr[mt][reg] = shift[co];
    }
  float v[2][4][4];   // [mt][yl][reg] membrane per (co, conv-pixel)
#pragma unroll
  for (int mt = 0; mt < 2; ++mt)
#pragma unroll
    for (int yl = 0; yl < 4; ++yl)
#pragma unroll
      for (int reg = 0; reg < 4; ++reg) v[mt][yl][reg] = 0.f;

#pragma unroll 1
  for (int t = 0; t < 8; ++t) {
    __syncthreads();
    // stage rows q4*4-1 .. q4*4+4 of image (t,b): [row 6][cg 8][x 18][ci_l 8]
    for (int i = tid; i < 3456; i += 256) {
      int j = i / 72, r = i - j * 72;
      int row = j >> 3, cg = j & 7;
      int xx = r >> 2, cp = r & 3;
      int yi = q4 * 4 - 1 + row, gx = xx - 1;
      unsigned val = 0u;
      if ((unsigned)yi < 16u && (unsigned)gx < 16u)
        val = ((const unsigned*)pool1)[(size_t)(t * 128 + b) * 8192 + cg * 1024 + yi * 64 + gx * 4 + cp];
      ((unsigned*)simg)[i] = val;
    }
    __syncthreads();

    f32x4 acc[2][4];
#pragma unroll
    for (int mt = 0; mt < 2; ++mt)
#pragma unroll
      for (int yl = 0; yl < 4; ++yl) acc[mt][yl] = (f32x4){0.f, 0.f, 0.f, 0.f};

    short8 a_cur[2][3];
#pragma unroll
    for (int mt = 0; mt < 2; ++mt) {
      int aoff = ((m0 + mt * 16 + xl) * 4 + q) * 8;
      a_cur[mt][0] = *(const short8*)(A2 + aoff);
      a_cur[mt][1] = *(const short8*)(A2 + 73728 + aoff);
      a_cur[mt][2] = *(const short8*)(A2 + 147456 + aoff);
    }

#pragma unroll 1
    for (int kc = 0; kc < 18; ++kc) {
      short8 a_nxt[2][3];
      if (kc < 17) {
#pragma unroll
        for (int mt = 0; mt < 2; ++mt) {
          int aoff = (((kc + 1) * 128 + m0 + mt * 16 + xl) * 4 + q) * 8;
          a_nxt[mt][0] = *(const short8*)(A2 + aoff);
          a_nxt[mt][1] = *(const short8*)(A2 + 73728 + aoff);
          a_nxt[mt][2] = *(const short8*)(A2 + 147456 + aoff);
        }
      } else {
#pragma unroll
        for (int mt = 0; mt < 2; ++mt)
#pragma unroll
          for (int sv = 0; sv < 3; ++sv) a_nxt[mt][sv] = a_cur[mt][sv];
      }
      int tap = kc >> 1;
      int dy = tap / 3, dx = tap - dy * 3;
      int cgq = (kc & 1) * 4 + q;
#pragma unroll
      for (int yl = 0; yl < 4; ++yl) {
        int baddr = (((yl + dy) * 8 + cgq) * 18 + (xl + dx)) * 8;
        short8 bb = *(const short8*)(simg + baddr);
#pragma unroll
        for (int mt = 0; mt < 2; ++mt) {
          acc[mt][yl] = __builtin_amdgcn_mfma_f32_16x16x32_bf16(a_cur[mt][0], bb, acc[mt][yl], 0, 0, 0);
          acc[mt][yl] = __builtin_amdgcn_mfma_f32_16x16x32_bf16(a_cur[mt][1], bb, acc[mt][yl], 0, 0, 0);
          acc[mt][yl] = __builtin_amdgcn_mfma_f32_16x16x32_bf16(a_cur[mt][2], bb, acc[mt][yl], 0, 0, 0);
        }
      }
#pragma unroll
      for (int mt = 0; mt < 2; ++mt)
#pragma unroll
        for (int sv = 0; sv < 3; ++sv) a_cur[mt][sv] = a_nxt[mt][sv];
    }

    // epilogue: BN + LIF + 2x2 pool -> shout [s_l][co]
#pragma unroll
    for (int mt = 0; mt < 2; ++mt)
#pragma unroll
      for (int reg = 0; reg < 4; ++reg) {
        float sarr[4];
#pragma unroll
        for (int yl = 0; yl < 4; ++yl) {
          float xv = fmaf(acc[mt][yl][reg], scr[mt][reg], shr[mt][reg]);
          float spk;
          LIF_STEP(v[mt][yl][reg], xv, spk);
          sarr[yl] = spk;
        }
#pragma unroll
        for (int rp = 0; rp < 2; ++rp) {
          float hp0 = sarr[2*rp]     + __shfl_xor(sarr[2*rp], 1);
          float hp1 = sarr[2*rp + 1] + __shfl_xor(sarr[2*rp + 1], 1);
          float vp = hp0 + hp1;
          if ((xl & 1) == 0) {
            int co = m0 + mt * 16 + q * 4 + reg;
            shout[(rp * 8 + (xl >> 1)) * 136 + co] = f2bf(0.25f * vp);
          }
        }
      }
    __syncthreads();
    // copy-out: 4 KB contiguous per (block,t): [tb][s=q4*16+s_l][ci]
    {
      int s_l = tid >> 4, ci8 = (tid & 15) * 8;
      uint4 vv = *(const uint4*)&shout[s_l * 136 + ci8];
      *(uint4*)(pool2 + ((size_t)(t * 128 + b) * 64 + q4 * 16 + s_l) * 128 + ci8) = vv;
    }
  }
}

// ---- fc1 (MFMA): partial[kb][o 256][tb 1024], split-K=16, no atomics. (validated) ----
__global__ __launch_bounds__(256, 2) void fc1_mfma(const unsigned short* __restrict__ pool2,
    const unsigned short* __restrict__ B1, float* __restrict__ partial) {
  int bx = blockIdx.x;            // 512 = kb(16) x tbt(16) x t_o(2)
  int t_o = bx & 1, tbt = (bx >> 1) & 15, kb = bx >> 5;
  int tid = threadIdx.x, wave = tid >> 6, lane = tid & 63;
  int xl = lane & 15, q = lane >> 4;
  int m0 = t_o * 128 + wave * 32;
  int n0 = tbt * 64;
  __shared__ unsigned short sB[64 * 40];
  f32x4 acc[2][4];
#pragma unroll
  for (int mt = 0; mt < 2; ++mt)
#pragma unroll
    for (int nt = 0; nt < 4; ++nt) acc[mt][nt] = (f32x4){0.f, 0.f, 0.f, 0.f};

#pragma unroll 1
  for (int kc0 = 0; kc0 < 16; ++kc0) {
    int kc = kb * 16 + kc0;
    __syncthreads();
    {
      int tb_l = tid >> 2, kq = tid & 3;
      uint4 vv = *(const uint4*)(pool2 + (size_t)(n0 + tb_l) * 8192 + kc * 32 + kq * 8);
      *(uint4*)(sB + tb_l * 40 + kq * 8) = vv;
    }
    __syncthreads();
    short8 a[2][3];
#pragma unroll
    for (int mt = 0; mt < 2; ++mt) {
      int aoff = ((kc * 256 + m0 + mt * 16 + xl) * 4 + q) * 8;
      a[mt][0] = *(const short8*)(B1 + aoff);
      a[mt][1] = *(const short8*)(B1 + 2097152 + aoff);
      a[mt][2] = *(const short8*)(B1 + 4194304 + aoff);
    }
#pragma unroll
    for (int nt = 0; nt < 4; ++nt) {
      short8 bb = *(const short8*)(sB + (nt * 16 + xl) * 40 + q * 8);
#pragma unroll
      for (int mt = 0; mt < 2; ++mt) {
        acc[mt][nt] = __builtin_amdgcn_mfma_f32_16x16x32_bf16(a[mt][0], bb, acc[mt][nt], 0, 0, 0);
        acc[mt][nt] = __builtin_amdgcn_mfma_f32_16x16x32_bf16(a[mt][1], bb, acc[mt][nt], 0, 0, 0);
        acc[mt][nt] = __builtin_amdgcn_mfma_f32_16x16x32_bf16(a[mt][2], bb, acc[mt][nt], 0, 0, 0);
      }
    }
  }
#pragma unroll
  for (int mt = 0; mt < 2; ++mt)
#pragma unroll
    for (int nt = 0; nt < 4; ++nt)
#pragma unroll
      for (int reg = 0; reg < 4; ++reg) {
        int o = m0 + mt * 16 + q * 4 + reg;
        partial[((size_t)kb * 256 + o) * 1024 + n0 + nt * 16 + xl] = acc[mt][nt][reg];
      }
}

// ---- reduce partials + LIF -> fc1 spikes [t][b][o]. ----
__global__ __launch_bounds__(256) void reduce_lif(const float* __restrict__ partial, float* __restrict__ fs) {
  int idx = blockIdx.x * 256 + threadIdx.x;
  int o = idx >> 7, b = idx & 127;
  float v = 0.f;
#pragma unroll 1
  for (int t = 0; t < 8; ++t) {
    float xv = 0.f;
#pragma unroll
    for (int kb = 0; kb < 16; ++kb)
      xv += partial[((size_t)kb * 256 + o) * 1024 + t * 128 + b];
    float s;
    LIF_STEP(v, xv, s);
    fs[t * 32768 + b * 256 + o] = s;
  }
}

__global__ __launch_bounds__(256) void fc2_kernel(const float* __restrict__ fs, const float* __restrict__ w,
                                                  const float* __restrict__ bias, float* __restrict__ outp) {
  int tb = blockIdx.x;
  __shared__ float sv[256];
  int tid = threadIdx.x;
  sv[tid] = fs[tb * 256 + tid];
  __syncthreads();
  if (tid < 10) {
    float a = bias[tid];
    const float* wr = w + tid * 256;
#pragma unroll 8
    for (int o = 0; o < 256; ++o) a = fmaf(sv[o], wr[o], a);
    outp[tb * 10 + tid] = a;
  }
}

extern "C" void kernel_launch(void* const* d_in, const int* in_sizes, int n_in,
                              void* d_out, int out_size, void* d_ws, size_t ws_size,
                              hipStream_t stream) {
  (void)in_sizes; (void)n_in; (void)out_size; (void)ws_size;
  const float* x_seq   = (const float*)d_in[0];
  const float* conv1_w = (const float*)d_in[1];
  const float* bn1_g   = (const float*)d_in[2];
  const float* bn1_b   = (const float*)d_in[3];
  const float* conv2_w = (const float*)d_in[4];
  const float* bn2_g   = (const float*)d_in[5];
  const float* bn2_b   = (const float*)d_in[6];
  const float* fc1_w   = (const float*)d_in[7];
  const float* fc2_w   = (const float*)d_in[8];
  const float* fc2_b   = (const float*)d_in[9];
  float* out = (float*)d_out;
  float* ws  = (float*)d_ws;

  unsigned short* pool1 = (unsigned short*)(ws + OFF_POOL1);
  float* fc1_part = ws + OFF_POOL1;
  unsigned short* pool2 = (unsigned short*)(ws + OFF_POOL2);
  float* fc1_s   = ws + OFF_FC1S;
  unsigned short* A2 = (unsigned short*)(ws + OFF_A2);
  unsigned short* B1 = (unsigned short*)(ws + OFF_B1);
  float* st      = ws + OFF_STATS;
  float* s1_sum = st;        float* s1_sq  = st + 64;
  float* bn1_sc = st + 128;  float* bn1_sh = st + 192;
  float* s2_sum = st + 256;  float* s2_sq  = st + 384;
  float* bn2_sc = st + 512;  float* bn2_sh = st + 640;

  zero_kernel<<<3, 256, 0, stream>>>(st, 768u);
  prep_w2<<<288, 256, 0, stream>>>(conv2_w, A2);
  prep_b1<<<8192, 256, 0, stream>>>(fc1_w, B1);
  conv1_pass1<<<1024, 256, 0, stream>>>(x_seq, conv1_w, s1_sum, s1_sq);
  finalize_bn<<<1, 64, 0, stream>>>(s1_sum, s1_sq, bn1_g, bn1_b, bn1_sc, bn1_sh, 1.0f / 1048576.0f);
  conv1_fused<<<1024, 256, 0, stream>>>(x_seq, conv1_w, bn1_sc, bn1_sh, pool1);
  conv2_pass1_mfma<<<1024, 256, 0, stream>>>(pool1, A2, s2_sum, s2_sq);
  finalize_bn<<<1, 128, 0, stream>>>(s2_sum, s2_sq, bn2_g, bn2_b, bn2_sc, bn2_sh, 1.0f / 262144.0f);
  conv2_fused_mfma<<<512, 256, 0, stream>>>(pool1, A2, bn2_sc, bn2_sh, pool2);
  fc1_mfma<<<512, 256, 0, stream>>>(pool2, B1, fc1_part);
  reduce_lif<<<128, 256, 0, stream>>>(fc1_part, fc1_s);
  fc2_kernel<<<1024, 256, 0, stream>>>(fc1_s, fc2_w, fc2_b, out);
}

// Round 6
// 636.462 us; speedup vs baseline: 1.0547x; 1.0547x over previous
//
#include <hip/hip_runtime.h>

// SNN forward. conv2 + fc1 on MFMA bf16, 3-way weight splits (hi+lo+lolo).
// R6: conv2 kernels re-tiled for occupancy (pass1: quarter-image grid 4096,
//     acc 32 regs; fused: row-pair grid 1024, t-pairs share A-frags);
//     stats atomics spread 64-way; prep_b1 writes coalesced (inverse map).

#define LIF_STEP(vv, xx, ss) do { \
    vv = fmaf((xx) - vv, 0.5f, vv); \
    ss = (vv >= 1.0f) ? 1.0f : 0.0f; \
    vv = (vv >= 1.0f) ? 0.0f : vv; \
  } while (0)

typedef __attribute__((ext_vector_type(8))) short short8;
typedef __attribute__((ext_vector_type(4))) float f32x4;

__device__ __forceinline__ float bf2f(unsigned short u) {
  return __uint_as_float(((unsigned)u) << 16);
}
__device__ __forceinline__ unsigned short f2bf(float f) {
  return (unsigned short)(__float_as_uint(f) >> 16);  // exact for k/4 spike values
}

// ---- workspace layout (float-slot offsets) ----
// pool1 bf16 [1024 tb][8 cg][16 py][16 px][8 ci_l] = 16,777,216 u16
//   (region reused AFTER conv2 as fc1 partials f32 [16 kb][256 o][1024 tb])
// pool2 bf16 [1024 tb][64 s][128 ci]               =  8,388,608 u16
#define OFF_POOL1   0u
#define OFF_POOL2   8388608u
#define OFF_STATS   12582912u   // f32 16,896: see sublayout below
#define OFF_FC1S    12599808u   // f32 262,144
#define OFF_A2      12861952u   // bf16 3x[18 kc][128 co][4 q][8 j]
#define OFF_B1      12972544u   // bf16 3x[256 kc][256 o][4 q][8 j]
// total 16,118,272 floats = 64.5 MB
// stats sublayout: s1_sum(64) s1_sq(64) bn1_sc(64) bn1_sh(64)
//                  bn2_sc(128) bn2_sh(128) s2_part[64 sp][2][128]
#define STATS_N 16896u

__global__ __launch_bounds__(256) void zero_kernel(float* __restrict__ p, unsigned n) {
  unsigned i = blockIdx.x * 256u + threadIdx.x;
  if (i < n) p[i] = 0.0f;
}

// conv2_w [co 128][ci 64][dy 3][dx 3] fp32 -> 3-way bf16 split in MFMA A-frag order
__global__ __launch_bounds__(256) void prep_w2(const float* __restrict__ w, unsigned short* __restrict__ A2) {
  int i = blockIdx.x * 256 + threadIdx.x;
  if (i >= 73728) return;
  int co = i / 576, r = i - co * 576;
  int ci = r / 9, t9 = r - ci * 9;
  int k = t9 * 64 + ci;
  int kc = k >> 5, q = (k >> 3) & 3, j = k & 7;
  int off = ((kc * 128 + co) * 4 + q) * 8 + j;
  float wv = w[i];
  unsigned short hi = f2bf(wv);
  float rem = wv - bf2f(hi);
  unsigned short lo = f2bf(rem);
  float rem2 = rem - bf2f(lo);
  A2[off] = hi;
  A2[73728 + off] = lo;
  A2[147456 + off] = f2bf(rem2);
}

// fc1_w -> 3-way split, inverse-mapped so WRITES are fully coalesced.
// thread i = output slot: i = kc*8192 + o*32 + q*8 + j; k = kc*32+q*8+j;
// permuted k = s*128+ci (pool2 is [s][ci]); k_orig = ci*64+s.
__global__ __launch_bounds__(256) void prep_b1(const float* __restrict__ w, unsigned short* __restrict__ B1) {
  int i = blockIdx.x * 256 + threadIdx.x;   // 2,097,152 total
  int j = i & 7, q = (i >> 3) & 3, o = (i >> 5) & 255, kc = i >> 13;
  int k = kc * 32 + q * 8 + j;
  int ci = k & 127, s = k >> 7;
  float wv = w[o * 8192 + ci * 64 + s];
  unsigned short hi = f2bf(wv);
  float rem = wv - bf2f(hi);
  unsigned short lo = f2bf(rem);
  float rem2 = rem - bf2f(lo);
  B1[i] = hi;
  B1[2097152 + i] = lo;
  B1[4194304 + i] = f2bf(rem2);
}

// ---- conv1 pass 1: stats only. (validated) ----
__global__ __launch_bounds__(256) void conv1_pass1(const float* __restrict__ x,
                                                   const float* __restrict__ w,
                                                   float* __restrict__ s_sum,
                                                   float* __restrict__ s_sq) {
  int tb = blockIdx.x;
  __shared__ float simg[3 * 32 * 36];
  int tid = threadIdx.x;
  const float* xb = x + tb * 3072;
  for (int i = tid; i < 3456; i += 256) {
    int ci = i / 1152, rem = i - ci * 1152;
    int y = rem / 36, px = rem - y * 36;
    int gx = px - 1;
    simg[i] = ((unsigned)gx < 32u) ? xb[(ci * 32 + y) * 32 + gx] : 0.0f;
  }
  __syncthreads();

  int cgrp = tid >> 3, rowthr = tid & 7;
  int c0 = cgrp * 2;
  float w0[27], w1[27];
#pragma unroll
  for (int j = 0; j < 27; ++j) { w0[j] = w[c0 * 27 + j]; w1[j] = w[c0 * 27 + 27 + j]; }

  float s1a = 0.f, s2a = 0.f, s1b = 0.f, s2b = 0.f;
  for (int task = 0; task < 8; ++task) {
    int y = rowthr + (task & 3) * 8;
    int x0 = (task >> 2) * 16;
    float acc0[16] = {0.f,0.f,0.f,0.f,0.f,0.f,0.f,0.f,0.f,0.f,0.f,0.f,0.f,0.f,0.f,0.f};
    float acc1[16] = {0.f,0.f,0.f,0.f,0.f,0.f,0.f,0.f,0.f,0.f,0.f,0.f,0.f,0.f,0.f,0.f};
#pragma unroll
    for (int ci = 0; ci < 3; ++ci) {
#pragma unroll
      for (int dy = 0; dy < 3; ++dy) {
        int yy = y + dy - 1;
        if (yy >= 0 && yy < 32) {
          const float* row = simg + (ci * 32 + yy) * 36 + x0;
          float rr[20];
#pragma unroll
          for (int q = 0; q < 5; ++q) {
            float4 f = *(const float4*)(row + q * 4);
            rr[q*4+0] = f.x; rr[q*4+1] = f.y; rr[q*4+2] = f.z; rr[q*4+3] = f.w;
          }
#pragma unroll
          for (int dx = 0; dx < 3; ++dx) {
            float wa = w0[ci*9 + dy*3 + dx], wb = w1[ci*9 + dy*3 + dx];
#pragma unroll
            for (int xi = 0; xi < 16; ++xi) {
              float v = rr[xi + dx];
              acc0[xi] = fmaf(wa, v, acc0[xi]);
              acc1[xi] = fmaf(wb, v, acc1[xi]);
            }
          }
        }
      }
    }
#pragma unroll
    for (int xi = 0; xi < 16; ++xi) {
      s1a += acc0[xi]; s2a = fmaf(acc0[xi], acc0[xi], s2a);
      s1b += acc1[xi]; s2b = fmaf(acc1[xi], acc1[xi], s2b);
    }
  }
#pragma unroll
  for (int off = 1; off < 8; off <<= 1) {
    s1a += __shfl_xor(s1a, off); s2a += __shfl_xor(s2a, off);
    s1b += __shfl_xor(s1b, off); s2b += __shfl_xor(s2b, off);
  }
  if (rowthr == 0) {
    atomicAdd(&s_sum[c0], s1a);     atomicAdd(&s_sq[c0], s2a);
    atomicAdd(&s_sum[c0 + 1], s1b); atomicAdd(&s_sq[c0 + 1], s2b);
  }
}

__global__ void finalize_bn(const float* __restrict__ sum, const float* __restrict__ sq,
                            const float* __restrict__ g, const float* __restrict__ b,
                            float* __restrict__ scale, float* __restrict__ shift, float inv_n) {
  int c = threadIdx.x;
  float mean = sum[c] * inv_n;
  float var = fmaxf(sq[c] * inv_n - mean * mean, 0.0f);
  float rstd = rsqrtf(var + 1e-5f);
  float sc = g[c] * rstd;
  scale[c] = sc;
  shift[c] = fmaf(-mean, sc, b[c]);
}

// layer-2 finalize: reduce 64-way spread partials [sp][2][128]
__global__ void finalize_bn2(const float* __restrict__ s2p,
                             const float* __restrict__ g, const float* __restrict__ b,
                             float* __restrict__ scale, float* __restrict__ shift, float inv_n) {
  int c = threadIdx.x;   // 128
  float s1 = 0.f, s2 = 0.f;
#pragma unroll 8
  for (int sp = 0; sp < 64; ++sp) {
    s1 += s2p[sp * 256 + c];
    s2 += s2p[sp * 256 + 128 + c];
  }
  float mean = s1 * inv_n;
  float var = fmaxf(s2 * inv_n - mean * mean, 0.0f);
  float rstd = rsqrtf(var + 1e-5f);
  float sc = g[c] * rstd;
  scale[c] = sc;
  shift[c] = fmaf(-mean, sc, b[c]);
}

// ---- conv1 pass 2: fused conv+BN+LIF+pool -> pool1 [tb][cg][py][px][ci_l 8]. (validated) ----
__global__ __launch_bounds__(256) void conv1_fused(const float* __restrict__ x,
    const float* __restrict__ w, const float* __restrict__ scale, const float* __restrict__ shift,
    unsigned short* __restrict__ pool1) {
  int b = blockIdx.x >> 3, cg = blockIdx.x & 7;
  int tid = threadIdx.x;
  int co_l = tid >> 5;
  int co = cg * 8 + co_l;
  int y = tid & 31;
  __shared__ float simg[3 * 34 * 36];
  __shared__ unsigned short shp[2112];
  float wreg[27];
#pragma unroll
  for (int j = 0; j < 27; ++j) wreg[j] = w[co * 27 + j];
  float sc = scale[co], sh = shift[co];
  float v[32];
#pragma unroll
  for (int i = 0; i < 32; ++i) v[i] = 0.f;

  for (int t = 0; t < 8; ++t) {
    int tb = t * 128 + b;
    const float* xb = x + tb * 3072;
    __syncthreads();
    for (int i = tid; i < 3672; i += 256) {
      int ci = i / 1224, r = i - ci * 1224;
      int yy = r / 36, xx = r - yy * 36;
      int gy = yy - 1, gx = xx - 1;
      simg[i] = ((unsigned)gy < 32u && (unsigned)gx < 32u) ? xb[(ci * 32 + gy) * 32 + gx] : 0.f;
    }
    __syncthreads();
    float acc[32];
#pragma unroll
    for (int i = 0; i < 32; ++i) acc[i] = 0.f;
#pragma unroll
    for (int ci = 0; ci < 3; ++ci) {
#pragma unroll
      for (int dy = 0; dy < 3; ++dy) {
        const float* row = simg + (ci * 34 + y + dy) * 36;
        float rr[36];
#pragma unroll
        for (int q = 0; q < 9; ++q) {
          float4 f = *(const float4*)(row + q * 4);
          rr[q*4+0]=f.x; rr[q*4+1]=f.y; rr[q*4+2]=f.z; rr[q*4+3]=f.w;
        }
#pragma unroll
        for (int dx = 0; dx < 3; ++dx) {
          float wv = wreg[ci * 9 + dy * 3 + dx];
#pragma unroll
          for (int xx2 = 0; xx2 < 32; ++xx2)
            acc[xx2] = fmaf(wv, rr[xx2 + dx], acc[xx2]);
        }
      }
    }
    float hp[16];
#pragma unroll
    for (int px = 0; px < 16; ++px) {
      float s0, s1, xv;
      xv = fmaf(acc[2*px],   sc, sh); LIF_STEP(v[2*px],   xv, s0);
      xv = fmaf(acc[2*px+1], sc, sh); LIF_STEP(v[2*px+1], xv, s1);
      hp[px] = s0 + s1;
    }
    unsigned short ob[16];
#pragma unroll
    for (int px = 0; px < 16; ++px) {
      float sum = hp[px] + __shfl_xor(hp[px], 1);
      ob[px] = f2bf(0.25f * sum);
    }
    if ((y & 1) == 0) {
      int py = y >> 1;
#pragma unroll
      for (int px = 0; px < 16; ++px)
        shp[py * 132 + px * 8 + co_l] = ob[px];
    }
    __syncthreads();
    {
      int o = (tid >> 4) * 132 + (tid & 15) * 8;
      uint2 lo = *(const uint2*)&shp[o];
      uint2 hi = *(const uint2*)&shp[o + 4];
      *(uint4*)(pool1 + (size_t)tb * 16384 + cg * 2048 + tid * 8) = make_uint4(lo.x, lo.y, hi.x, hi.y);
    }
  }
}

// ---- conv2 pass 1 (MFMA): stats only. Block = (tb, row-quarter); grid 4096. ----
// acc[2][4]=32 regs (was 128) -> ~2x waves/SIMD. Stats -> 64-way spread partials.
__global__ __launch_bounds__(256, 2) void conv2_pass1_mfma(const unsigned short* __restrict__ pool1,
    const unsigned short* __restrict__ A2, float* __restrict__ s2p) {
  int bx = blockIdx.x;
  int tb = bx >> 2, q4 = bx & 3;
  int sp = bx & 63;
  __shared__ unsigned short simg[6 * 8 * 18 * 8];   // 13,824 B
  int tid = threadIdx.x;
  const unsigned* src = (const unsigned*)(pool1 + (size_t)tb * 16384);
  unsigned* dstw = (unsigned*)simg;
  for (int i = tid; i < 3456; i += 256) {
    int cp = i & 3, rest = i >> 2;
    int jj = rest / 18, xx = rest - jj * 18;
    int cg = jj & 7, row_l = jj >> 3;
    int yi = q4 * 4 - 1 + row_l, gx = xx - 1;
    unsigned val = 0u;
    if ((unsigned)yi < 16u && (unsigned)gx < 16u)
      val = src[cg * 1024 + yi * 64 + gx * 4 + cp];
    dstw[i] = val;
  }
  __syncthreads();

  int wave = tid >> 6, lane = tid & 63;
  int xl = lane & 15, q = lane >> 4;
  int m0 = wave * 32;
  f32x4 acc[2][4];
#pragma unroll
  for (int mt = 0; mt < 2; ++mt)
#pragma unroll
    for (int yl = 0; yl < 4; ++yl) acc[mt][yl] = (f32x4){0.f, 0.f, 0.f, 0.f};

  short8 a_cur[2][3];
#pragma unroll
  for (int mt = 0; mt < 2; ++mt) {
    int aoff = ((m0 + mt * 16 + xl) * 4 + q) * 8;
    a_cur[mt][0] = *(const short8*)(A2 + aoff);
    a_cur[mt][1] = *(const short8*)(A2 + 73728 + aoff);
    a_cur[mt][2] = *(const short8*)(A2 + 147456 + aoff);
  }

#pragma unroll 1
  for (int kc = 0; kc < 18; ++kc) {
    short8 a_nxt[2][3];
    if (kc < 17) {
#pragma unroll
      for (int mt = 0; mt < 2; ++mt) {
        int aoff = (((kc + 1) * 128 + m0 + mt * 16 + xl) * 4 + q) * 8;
        a_nxt[mt][0] = *(const short8*)(A2 + aoff);
        a_nxt[mt][1] = *(const short8*)(A2 + 73728 + aoff);
        a_nxt[mt][2] = *(const short8*)(A2 + 147456 + aoff);
      }
    } else {
#pragma unroll
      for (int mt = 0; mt < 2; ++mt)
#pragma unroll
        for (int sv = 0; sv < 3; ++sv) a_nxt[mt][sv] = a_cur[mt][sv];
    }
    int tap = kc >> 1;
    int dy = tap / 3, dx = tap - dy * 3;
    int cgq = (kc & 1) * 4 + q;
#pragma unroll
    for (int yl = 0; yl < 4; ++yl) {
      int baddr = (((yl + dy) * 8 + cgq) * 18 + (xl + dx)) * 8;
      short8 bb = *(const short8*)(simg + baddr);
#pragma unroll
      for (int mt = 0; mt < 2; ++mt) {
        acc[mt][yl] = __builtin_amdgcn_mfma_f32_16x16x32_bf16(a_cur[mt][0], bb, acc[mt][yl], 0, 0, 0);
        acc[mt][yl] = __builtin_amdgcn_mfma_f32_16x16x32_bf16(a_cur[mt][1], bb, acc[mt][yl], 0, 0, 0);
        acc[mt][yl] = __builtin_amdgcn_mfma_f32_16x16x32_bf16(a_cur[mt][2], bb, acc[mt][yl], 0, 0, 0);
      }
    }
#pragma unroll
    for (int mt = 0; mt < 2; ++mt)
#pragma unroll
      for (int sv = 0; sv < 3; ++sv) a_cur[mt][sv] = a_nxt[mt][sv];
  }
#pragma unroll
  for (int mt = 0; mt < 2; ++mt)
#pragma unroll
    for (int reg = 0; reg < 4; ++reg) {
      float s1 = 0.f, s2 = 0.f;
#pragma unroll
      for (int yl = 0; yl < 4; ++yl) {
        float val = acc[mt][yl][reg];
        s1 += val; s2 = fmaf(val, val, s2);
      }
#pragma unroll
      for (int off = 1; off < 16; off <<= 1) {
        s1 += __shfl_xor(s1, off); s2 += __shfl_xor(s2, off);
      }
      if (xl == 0) {
        int co = m0 + mt * 16 + q * 4 + reg;
        atomicAdd(&s2p[sp * 256 + co], s1);
        atomicAdd(&s2p[sp * 256 + 128 + co], s2);
      }
    }
}

// ---- conv2 pass 2 (MFMA): fused conv+BN+LIF+pool. Block = (b, row-pair); grid 1024. ----
// t-pairs per stage share A-frags (halves A L2 traffic); membrane in regs across T.
__global__ __launch_bounds__(256, 2) void conv2_fused_mfma(const unsigned short* __restrict__ pool1,
    const unsigned short* __restrict__ A2,
    const float* __restrict__ scale, const float* __restrict__ shift,
    unsigned short* __restrict__ pool2) {
  int b = blockIdx.x >> 3, q8 = blockIdx.x & 7;
  __shared__ unsigned short simg[2 * 4 * 8 * 18 * 8];  // 18,432 B : [t_l][row 4][cg][x 18][ci_l]
  __shared__ unsigned short shout[2 * 8 * 136];        // 4,352 B : [t_l][px 8][co 128+pad]
  int tid = threadIdx.x, wave = tid >> 6, lane = tid & 63;
  int xl = lane & 15, q = lane >> 4;
  int m0 = wave * 32;

  float scr[2][4], shr[2][4];
#pragma unroll
  for (int mt = 0; mt < 2; ++mt)
#pragma unroll
    for (int reg = 0; reg < 4; ++reg) {
      int co = m0 + mt * 16 + q * 4 + reg;
      scr[mt][reg] = scale[co]; shr[mt][reg] = shift[co];
    }
  float v[2][2][4];   // [mt][yl][reg] membrane per (co, conv row 2*q8+yl, col xl)
#pragma unroll
  for (int mt = 0; mt < 2; ++mt)
#pragma unroll
    for (int yl = 0; yl < 2; ++yl)
#pragma unroll
      for (int reg = 0; reg < 4; ++reg) v[mt][yl][reg] = 0.f;

#pragma unroll 1
  for (int tg = 0; tg < 4; ++tg) {
    __syncthreads();
    // stage rows 2*q8-1 .. 2*q8+2 of images (tg*2, tg*2+1)
    for (int i = tid; i < 4608; i += 256) {
      int t_l = (i >= 2304) ? 1 : 0;
      int r0 = i - t_l * 2304;
      int cp = r0 & 3, rest = r0 >> 2;
      int jj = rest / 18, xx = rest - jj * 18;
      int cg = jj & 7, row_l = jj >> 3;
      int yi = q8 * 2 - 1 + row_l, gx = xx - 1;
      unsigned val = 0u;
      if ((unsigned)yi < 16u && (unsigned)gx < 16u)
        val = ((const unsigned*)pool1)[(size_t)((tg * 2 + t_l) * 128 + b) * 8192 + cg * 1024 + yi * 64 + gx * 4 + cp];
      ((unsigned*)simg)[i] = val;
    }
    __syncthreads();

    f32x4 acc[2][2][2];   // [t_l][mt][yl]
#pragma unroll
    for (int t_l = 0; t_l < 2; ++t_l)
#pragma unroll
      for (int mt = 0; mt < 2; ++mt)
#pragma unroll
        for (int yl = 0; yl < 2; ++yl) acc[t_l][mt][yl] = (f32x4){0.f, 0.f, 0.f, 0.f};

    short8 a_cur[2][3];
#pragma unroll
    for (int mt = 0; mt < 2; ++mt) {
      int aoff = ((m0 + mt * 16 + xl) * 4 + q) * 8;
      a_cur[mt][0] = *(const short8*)(A2 + aoff);
      a_cur[mt][1] = *(const short8*)(A2 + 73728 + aoff);
      a_cur[mt][2] = *(const short8*)(A2 + 147456 + aoff);
    }

#pragma unroll 1
    for (int kc = 0; kc < 18; ++kc) {
      short8 a_nxt[2][3];
      if (kc < 17) {
#pragma unroll
        for (int mt = 0; mt < 2; ++mt) {
          int aoff = (((kc + 1) * 128 + m0 + mt * 16 + xl) * 4 + q) * 8;
          a_nxt[mt][0] = *(const short8*)(A2 + aoff);
          a_nxt[mt][1] = *(const short8*)(A2 + 73728 + aoff);
          a_nxt[mt][2] = *(const short8*)(A2 + 147456 + aoff);
        }
      } else {
#pragma unroll
        for (int mt = 0; mt < 2; ++mt)
#pragma unroll
          for (int sv = 0; sv < 3; ++sv) a_nxt[mt][sv] = a_cur[mt][sv];
      }
      int tap = kc >> 1;
      int dy = tap / 3, dx = tap - dy * 3;
      int cgq = (kc & 1) * 4 + q;
#pragma unroll
      for (int t_l = 0; t_l < 2; ++t_l) {
#pragma unroll
        for (int yl = 0; yl < 2; ++yl) {
          int baddr = t_l * 4608 + (((yl + dy) * 8 + cgq) * 18 + (xl + dx)) * 8;
          short8 bb = *(const short8*)(simg + baddr);
#pragma unroll
          for (int mt = 0; mt < 2; ++mt) {
            acc[t_l][mt][yl] = __builtin_amdgcn_mfma_f32_16x16x32_bf16(a_cur[mt][0], bb, acc[t_l][mt][yl], 0, 0, 0);
            acc[t_l][mt][yl] = __builtin_amdgcn_mfma_f32_16x16x32_bf16(a_cur[mt][1], bb, acc[t_l][mt][yl], 0, 0, 0);
            acc[t_l][mt][yl] = __builtin_amdgcn_mfma_f32_16x16x32_bf16(a_cur[mt][2], bb, acc[t_l][mt][yl], 0, 0, 0);
          }
        }
      }
#pragma unroll
      for (int mt = 0; mt < 2; ++mt)
#pragma unroll
        for (int sv = 0; sv < 3; ++sv) a_cur[mt][sv] = a_nxt[mt][sv];
    }

    // epilogue (LIF order: t_l 0 then 1), both t_l into shout, one sync, copy-out
#pragma unroll
    for (int t_l = 0; t_l < 2; ++t_l) {
#pragma unroll
      for (int mt = 0; mt < 2; ++mt)
#pragma unroll
        for (int reg = 0; reg < 4; ++reg) {
          float sarr[2];
#pragma unroll
          for (int yl = 0; yl < 2; ++yl) {
            float xv = fmaf(acc[t_l][mt][yl][reg], scr[mt][reg], shr[mt][reg]);
            float spk;
            LIF_STEP(v[mt][yl][reg], xv, spk);
            sarr[yl] = spk;
          }
          float hp0 = sarr[0] + __shfl_xor(sarr[0], 1);
          float hp1 = sarr[1] + __shfl_xor(sarr[1], 1);
          float vp = hp0 + hp1;
          if ((xl & 1) == 0) {
            int co = m0 + mt * 16 + q * 4 + reg;
            shout[t_l * 1088 + (xl >> 1) * 136 + co] = f2bf(0.25f * vp);
          }
        }
    }
    __syncthreads();
    // copy-out: pool2 [tb][s = q8*8 + px][ci], 2 KB contiguous per (block, t)
    {
      int px = tid >> 5, ci4 = (tid & 31) * 4;
#pragma unroll
      for (int t_l = 0; t_l < 2; ++t_l) {
        uint2 vv = *(const uint2*)&shout[t_l * 1088 + px * 136 + ci4];
        *(uint2*)(pool2 + ((size_t)((tg * 2 + t_l) * 128 + b) * 64 + q8 * 8 + px) * 128 + ci4) = vv;
      }
    }
  }
}

// ---- fc1 (MFMA): partial[kb][o 256][tb 1024], split-K=16, no atomics. (validated) ----
__global__ __launch_bounds__(256, 2) void fc1_mfma(const unsigned short* __restrict__ pool2,
    const unsigned short* __restrict__ B1, float* __restrict__ partial) {
  int bx = blockIdx.x;            // 512 = kb(16) x tbt(16) x t_o(2)
  int t_o = bx & 1, tbt = (bx >> 1) & 15, kb = bx >> 5;
  int tid = threadIdx.x, wave = tid >> 6, lane = tid & 63;
  int xl = lane & 15, q = lane >> 4;
  int m0 = t_o * 128 + wave * 32;
  int n0 = tbt * 64;
  __shared__ unsigned short sB[64 * 40];
  f32x4 acc[2][4];
#pragma unroll
  for (int mt = 0; mt < 2; ++mt)
#pragma unroll
    for (int nt = 0; nt < 4; ++nt) acc[mt][nt] = (f32x4){0.f, 0.f, 0.f, 0.f};

#pragma unroll 1
  for (int kc0 = 0; kc0 < 16; ++kc0) {
    int kc = kb * 16 + kc0;
    __syncthreads();
    {
      int tb_l = tid >> 2, kq = tid & 3;
      uint4 vv = *(const uint4*)(pool2 + (size_t)(n0 + tb_l) * 8192 + kc * 32 + kq * 8);
      *(uint4*)(sB + tb_l * 40 + kq * 8) = vv;
    }
    __syncthreads();
    short8 a[2][3];
#pragma unroll
    for (int mt = 0; mt < 2; ++mt) {
      int aoff = ((kc * 256 + m0 + mt * 16 + xl) * 4 + q) * 8;
      a[mt][0] = *(const short8*)(B1 + aoff);
      a[mt][1] = *(const short8*)(B1 + 2097152 + aoff);
      a[mt][2] = *(const short8*)(B1 + 4194304 + aoff);
    }
#pragma unroll
    for (int nt = 0; nt < 4; ++nt) {
      short8 bb = *(const short8*)(sB + (nt * 16 + xl) * 40 + q * 8);
#pragma unroll
      for (int mt = 0; mt < 2; ++mt) {
        acc[mt][nt] = __builtin_amdgcn_mfma_f32_16x16x32_bf16(a[mt][0], bb, acc[mt][nt], 0, 0, 0);
        acc[mt][nt] = __builtin_amdgcn_mfma_f32_16x16x32_bf16(a[mt][1], bb, acc[mt][nt], 0, 0, 0);
        acc[mt][nt] = __builtin_amdgcn_mfma_f32_16x16x32_bf16(a[mt][2], bb, acc[mt][nt], 0, 0, 0);
      }
    }
  }
#pragma unroll
  for (int mt = 0; mt < 2; ++mt)
#pragma unroll
    for (int nt = 0; nt < 4; ++nt)
#pragma unroll
      for (int reg = 0; reg < 4; ++reg) {
        int o = m0 + mt * 16 + q * 4 + reg;
        partial[((size_t)kb * 256 + o) * 1024 + n0 + nt * 16 + xl] = acc[mt][nt][reg];
      }
}

// ---- reduce partials + LIF -> fc1 spikes [t][b][o]. ----
__global__ __launch_bounds__(256) void reduce_lif(const float* __restrict__ partial, float* __restrict__ fs) {
  int idx = blockIdx.x * 256 + threadIdx.x;
  int o = idx >> 7, b = idx & 127;
  float v = 0.f;
#pragma unroll 1
  for (int t = 0; t < 8; ++t) {
    float xv = 0.f;
#pragma unroll
    for (int kb = 0; kb < 16; ++kb)
      xv += partial[((size_t)kb * 256 + o) * 1024 + t * 128 + b];
    float s;
    LIF_STEP(v, xv, s);
    fs[t * 32768 + b * 256 + o] = s;
  }
}

__global__ __launch_bounds__(256) void fc2_kernel(const float* __restrict__ fs, const float* __restrict__ w,
                                                  const float* __restrict__ bias, float* __restrict__ outp) {
  int tb = blockIdx.x;
  __shared__ float sv[256];
  int tid = threadIdx.x;
  sv[tid] = fs[tb * 256 + tid];
  __syncthreads();
  if (tid < 10) {
    float a = bias[tid];
    const float* wr = w + tid * 256;
#pragma unroll 8
    for (int o = 0; o < 256; ++o) a = fmaf(sv[o], wr[o], a);
    outp[tb * 10 + tid] = a;
  }
}

extern "C" void kernel_launch(void* const* d_in, const int* in_sizes, int n_in,
                              void* d_out, int out_size, void* d_ws, size_t ws_size,
                              hipStream_t stream) {
  (void)in_sizes; (void)n_in; (void)out_size; (void)ws_size;
  const float* x_seq   = (const float*)d_in[0];
  const float* conv1_w = (const float*)d_in[1];
  const float* bn1_g   = (const float*)d_in[2];
  const float* bn1_b   = (const float*)d_in[3];
  const float* conv2_w = (const float*)d_in[4];
  const float* bn2_g   = (const float*)d_in[5];
  const float* bn2_b   = (const float*)d_in[6];
  const float* fc1_w   = (const float*)d_in[7];
  const float* fc2_w   = (const float*)d_in[8];
  const float* fc2_b   = (const float*)d_in[9];
  float* out = (float*)d_out;
  float* ws  = (float*)d_ws;

  unsigned short* pool1 = (unsigned short*)(ws + OFF_POOL1);
  float* fc1_part = ws + OFF_POOL1;
  unsigned short* pool2 = (unsigned short*)(ws + OFF_POOL2);
  float* fc1_s   = ws + OFF_FC1S;
  unsigned short* A2 = (unsigned short*)(ws + OFF_A2);
  unsigned short* B1 = (unsigned short*)(ws + OFF_B1);
  float* st      = ws + OFF_STATS;
  float* s1_sum = st;        float* s1_sq  = st + 64;
  float* bn1_sc = st + 128;  float* bn1_sh = st + 192;
  float* bn2_sc = st + 256;  float* bn2_sh = st + 384;
  float* s2p    = st + 512;  // [64 sp][2][128]

  zero_kernel<<<66, 256, 0, stream>>>(st, STATS_N);
  prep_w2<<<288, 256, 0, stream>>>(conv2_w, A2);
  prep_b1<<<8192, 256, 0, stream>>>(fc1_w, B1);
  conv1_pass1<<<1024, 256, 0, stream>>>(x_seq, conv1_w, s1_sum, s1_sq);
  finalize_bn<<<1, 64, 0, stream>>>(s1_sum, s1_sq, bn1_g, bn1_b, bn1_sc, bn1_sh, 1.0f / 1048576.0f);
  conv1_fused<<<1024, 256, 0, stream>>>(x_seq, conv1_w, bn1_sc, bn1_sh, pool1);
  conv2_pass1_mfma<<<4096, 256, 0, stream>>>(pool1, A2, s2p);
  finalize_bn2<<<1, 128, 0, stream>>>(s2p, bn2_g, bn2_b, bn2_sc, bn2_sh, 1.0f / 262144.0f);
  conv2_fused_mfma<<<1024, 256, 0, stream>>>(pool1, A2, bn2_sc, bn2_sh, pool2);
  fc1_mfma<<<512, 256, 0, stream>>>(pool2, B1, fc1_part);
  reduce_lif<<<128, 256, 0, stream>>>(fc1_part, fc1_s);
  fc2_kernel<<<1024, 256, 0, stream>>>(fc1_s, fc2_w, fc2_b, out);
}